// Round 4
// baseline (478.418 us; speedup 1.0000x reference)
//
#include <hip/hip_runtime.h>
#include <cstdint>
#include <climits>
#include <cstddef>

#define TK 13
#define MAXG 128

__device__ __forceinline__ float iou_fn(const float4 pb, const float4 gb){
  float pa = (pb.z - pb.x) * (pb.w - pb.y);
  float ga = (gb.z - gb.x) * (gb.w - gb.y);
  float ltx = fmaxf(pb.x, gb.x), lty = fmaxf(pb.y, gb.y);
  float rbx = fminf(pb.z, gb.z), rby = fminf(pb.w, gb.w);
  float w = fmaxf(rbx - ltx, 0.0f), h = fmaxf(rby - lty, 0.0f);
  float inter = w * h;
  float uni = pa + ga - inter;
  return inter / fmaxf(uni, 1e-6f);
}

__device__ __forceinline__ float sigmoid_f(float x){ return 1.0f / (1.0f + expf(-x)); }

// Same expression order as R0-R3 (passed absmax 0) — do not alter.
__device__ __forceinline__ float cost_full(float iou, float s, float dist){
  float sig = sigmoid_f(s);
  float iouc = -logf(iou + 1e-7f) * 3.0f;
  float scale = iou - sig;
  float bce = fmaxf(s, 0.0f) + log1pf(expf(-fabsf(s))) - s * iou;
  float cls = bce * scale * scale;
  float soft = powf(10.0f, dist - 3.0f);
  return cls + iouc + soft;
}

// descending u64 sorted-insert, list[0] largest; sentinel 0
__device__ __forceinline__ void ins13(unsigned long long* a, unsigned long long k){
  if (k <= a[TK-1]) return;
  #pragma unroll
  for (int j = 0; j < TK; ++j){
    if (k > a[j]){ unsigned long long t = a[j]; a[j] = k; k = t; }
  }
}

__device__ __forceinline__ void bfly_max_u64(unsigned long long &v, int &l){
  #pragma unroll
  for (int off = 32; off >= 1; off >>= 1){
    unsigned long long ov = __shfl_xor(v, off);
    int ol = __shfl_xor(l, off);
    if (ov > v){ v = ov; l = ol; }
  }
}

// 13th-largest of one key per lane (0 if fewer than 13 nonzero). All lanes get it.
__device__ __forceinline__ unsigned long long red13(unsigned long long k, int lane){
  unsigned long long w = 0;
  for (int r = 0; r < TK; ++r){
    unsigned long long v = k; int l = lane;
    bfly_max_u64(v, l);
    w = v;
    if (lane == l) k = 0;
  }
  return w;
}

// merge 64 sorted desc lists (one per lane, in LDS); r-th winner left on lane r.
__device__ __forceinline__ unsigned long long merge64(const unsigned long long* L, int lane){
  int ptr = 0;
  unsigned long long h = L[lane*TK];
  unsigned long long w = 0;
  for (int r = 0; r < TK; ++r){
    unsigned long long v = h; int l = lane;
    bfly_max_u64(v, l);
    if (lane == r) w = v;
    if (lane == l){ ptr++; h = (ptr < TK) ? L[lane*TK + ptr] : 0ull; }
  }
  return w;
}

// Kernel A: valid_mask + acc init.
__global__ __launch_bounds__(256) void k_valid(
    const float4* __restrict__ priors, const float4* __restrict__ gtb,
    const float* __restrict__ pad, uint8_t* __restrict__ valid,
    unsigned int* __restrict__ acc, int P, int G)
{
  int b = blockIdx.y;
  int p = blockIdx.x * 256 + threadIdx.x;
  __shared__ float4 sg[MAXG];
  __shared__ float sp[MAXG];
  for (int i = threadIdx.x; i < G; i += 256){ sg[i] = gtb[b*G + i]; sp[i] = pad[b*G + i]; }
  __syncthreads();
  if (p >= P) return;
  float4 pr = priors[p];
  bool v = false;
  for (int g = 0; g < G; ++g){
    float4 gb = sg[g];
    bool ig = (pr.x > gb.x) && (pr.y > gb.y) && (gb.z > pr.x) && (gb.w > pr.y);
    v = v || (ig && sp[g] > 0.5f);
  }
  size_t o = (size_t)b * P + p;
  valid[o] = v ? 1 : 0;
  acc[o] = 0u;
}

// Kernel B1: one single-wave block per (b,g,slice). Pruned scan of the slice,
// per-lane top-13 u64 lists; early block-level bound activation at it={0,1,2,8};
// exact slice top-13 per criterion written to ws.
__global__ __launch_bounds__(64) void k_scan(
    const float4* __restrict__ pred_bboxes, const float* __restrict__ pred_scores,
    const float4* __restrict__ priors, const int* __restrict__ gt_labels,
    const float4* __restrict__ gtbb, const float* __restrict__ pad,
    const uint8_t* __restrict__ validb,
    unsigned long long* __restrict__ wsM, unsigned long long* __restrict__ wsC,
    unsigned long long* __restrict__ wsI,
    int P, int G, int C, int S, int PS)
{
  int bg = blockIdx.x;
  int s  = blockIdx.y;
  if (pad[bg] <= 0.5f) return;
  int b = bg / G;
  int lane = threadIdx.x;
  float4 gb = gtbb[bg];
  int lbl = gt_labels[bg];
  float gcx = (gb.x + gb.z) * 0.5f, gcy = (gb.y + gb.w) * 0.5f;
  size_t bP = (size_t)b * P;

  __shared__ unsigned long long slist[64 * TK];
  __shared__ unsigned int shw[2];  // [0]=cost 13th bits (min), [1]=metric 13th bits (max)
  if (lane == 0){ shw[0] = __float_as_uint(1e38f); shw[1] = 0u; }
  __syncthreads();

  unsigned long long ml[TK], cl[TK];
  float ivl[TK];
  #pragma unroll
  for (int j = 0; j < TK; ++j){ ml[j] = 0ull; cl[j] = 0ull; ivl[j] = -1.0f; }

  unsigned cmLast = 0u; float thr = 1e30f;
  int p0 = s * PS;
  int p1 = p0 + PS; if (p1 > P) p1 = P;
  int it = 0;
  for (int p = p0 + lane; p < p1; p += 64, ++it){
    float4 pr = priors[p];
    float4 pb = pred_bboxes[bP + p];
    float iou = iou_fn(pb, gb);
    if (iou > ivl[TK-1]){
      float v = iou;
      #pragma unroll
      for (int j = 0; j < TK; ++j){ if (v > ivl[j]){ float t = ivl[j]; ivl[j] = v; v = t; } }
    }
    bool ig = (pr.x > gb.x) && (pr.y > gb.y) && (gb.z > pr.x) && (gb.w > pr.y);
    unsigned cm = shw[0];
    if (cm != cmLast){ cmLast = cm; thr = 3.0f + log10f(__uint_as_float(cm) * 1.00002f + 1e-6f); }
    float mB = __uint_as_float(shw[1]);
    float i2 = iou * iou;
    float bnd = (i2 * i2) * i2 * 1.000002f;        // >= sigmoid*powf(iou,6)
    bool need_m = ig && !(bnd < mB);
    bool vld = validb[bP + p] != 0;
    float dist = 0.0f; bool need_c = false;
    if (vld){
      float dx = pr.x - gcx, dy = pr.y - gcy;
      dist = sqrtf(dx*dx + dy*dy) / pr.z;
      need_c = !(dist > thr);
    }
    float sc = 0.0f;
    if (need_m || need_c) sc = pred_scores[(bP + p) * C + lbl];
    if (need_m){
      float met = sigmoid_f(sc) * powf(iou, 6.0f);
      unsigned long long k = ((unsigned long long)__float_as_uint(met) << 32)
                           | (unsigned)~(unsigned)((p << 1) | 1);
      ins13(ml, k);
      unsigned m13 = (unsigned)(ml[TK-1] >> 32);
      if (ml[TK-1] != 0ull && __uint_as_float(m13) > mB) atomicMax(&shw[1], m13);
    } else if (!ig){
      ins13(ml, (unsigned long long)(unsigned)~(unsigned)(p << 1));  // metric==0, index tie
    }
    if (!vld || need_c){
      float c = vld ? cost_full(iou, sc, dist) : 1e8f;
      unsigned long long k = ~(((unsigned long long)__float_as_uint(c) << 32) | (unsigned)p);
      if (k > cl[TK-1]){
        ins13(cl, k);
        if (cl[TK-1] != 0ull){
          unsigned cb = (unsigned)((~cl[TK-1]) >> 32);
          if (cb < cmLast || cmLast == 0u) atomicMin(&shw[0], cb);
        }
      }
    }
    // early bound activation: 13th-best of lane-best entries (sound: 13 better entries exist)
    if (it <= 2 || it == 8){
      unsigned long long wc = red13(cl[0], lane);
      if (lane == 0 && wc != 0ull) atomicMin(&shw[0], (unsigned)((~wc) >> 32));
      if (it == 0){
        unsigned long long wm = red13(ml[0], lane);
        if (lane == 0 && wm != 0ull){
          unsigned vb = (unsigned)(wm >> 32);
          if (vb) atomicMax(&shw[1], vb);
        }
      }
    }
  }

  size_t base = ((size_t)bg * S + s) * TK;
  // metric
  #pragma unroll
  for (int j = 0; j < TK; ++j) slist[lane*TK + j] = ml[j];
  __syncthreads();
  {
    unsigned long long w = merge64(slist, lane);
    if (lane < TK) wsM[base + lane] = w;
  }
  __syncthreads();
  // iou: keys with block-unique low bits; rewrite low bits globally unique on write
  #pragma unroll
  for (int j = 0; j < TK; ++j){
    float v = ivl[j] > 0.0f ? ivl[j] : 0.0f;
    slist[lane*TK + j] = ((unsigned long long)__float_as_uint(v) << 32) | (unsigned)(lane*TK + j + 1);
  }
  __syncthreads();
  {
    unsigned long long w = merge64(slist, lane);
    if (lane < TK) wsI[base + lane] = (w & 0xFFFFFFFF00000000ull) | (unsigned)(s*TK + lane + 1);
  }
  __syncthreads();
  // cost
  #pragma unroll
  for (int j = 0; j < TK; ++j) slist[lane*TK + j] = cl[j];
  __syncthreads();
  {
    unsigned long long w = merge64(slist, lane);
    if (lane < TK) wsC[base + lane] = w;
  }
}

// Kernel B2: one wave per (b,g). Merge S*13 slice winners per criterion (keys
// globally unique since p is partitioned across slices); scatter into acc.
__global__ __launch_bounds__(64) void k_merge(
    const unsigned long long* __restrict__ wsM, const unsigned long long* __restrict__ wsC,
    const unsigned long long* __restrict__ wsI, const float* __restrict__ pad,
    unsigned int* __restrict__ acc, int P, int G, int S)
{
  int bg = blockIdx.x;
  if (pad[bg] <= 0.5f) return;
  int b = bg / G;
  int g = bg - b * G;
  int lane = threadIdx.x;
  size_t bP = (size_t)b * P;
  int n = S * TK;
  // ---- metric -> fg marks ----
  {
    const unsigned long long* base = wsM + (size_t)bg * n;
    unsigned long long k0 = (lane < n) ? base[lane] : 0ull;
    unsigned long long k1 = (lane + 64 < n) ? base[lane + 64] : 0ull;
    for (int r = 0; r < TK; ++r){
      unsigned long long m = k0 > k1 ? k0 : k1; int l = lane;
      bfly_max_u64(m, l);
      if (m == 0ull) break;
      if (lane == 0){
        unsigned ix = ~(unsigned)(m & 0xFFFFFFFFull);
        if (ix & 1u) atomicOr(&acc[bP + (ix >> 1)], 2u);
      }
      if (lane == l){ if (k0 == m) k0 = 0ull; else k1 = 0ull; }
    }
  }
  // ---- iou -> dynamic_k (desc-order sum) ----
  int kd;
  {
    const unsigned long long* base = wsI + (size_t)bg * n;
    unsigned long long k0 = (lane < n) ? base[lane] : 0ull;
    unsigned long long k1 = (lane + 64 < n) ? base[lane + 64] : 0ull;
    float ksum = 0.0f;
    for (int r = 0; r < TK; ++r){
      unsigned long long m = k0 > k1 ? k0 : k1; int l = lane;
      bfly_max_u64(m, l);
      ksum += __uint_as_float((unsigned)(m >> 32));
      if (lane == l){ if (k0 == m) k0 = 0ull; else k1 = 0ull; }
    }
    kd = (int)ksum; if (kd < 1) kd = 1;
  }
  // ---- cost -> emit first kd selections ----
  {
    const unsigned long long* base = wsC + (size_t)bg * n;
    unsigned long long k0 = (lane < n) ? base[lane] : 0ull;
    unsigned long long k1 = (lane + 64 < n) ? base[lane + 64] : 0ull;
    for (int r = 0; r < kd; ++r){
      unsigned long long m = k0 > k1 ? k0 : k1; int l = lane;
      bfly_max_u64(m, l);
      if (m == 0ull) break;
      if (lane == 0){
        unsigned long long key = ~m;
        unsigned p = (unsigned)(key & 0xFFFFFFFFull);
        atomicAdd(&acc[bP + p], (1u << 17) | ((unsigned)g << 2));
      }
      if (lane == l){ if (k0 == m) k0 = 0ull; else k1 = 0ull; }
    }
  }
}

// Kernel C: per (b,p) decode acc; multi-match -> dist-pruned argmin-cost; write outputs.
__global__ __launch_bounds__(256) void k_final(
    const float4* __restrict__ pred_bboxes, const float* __restrict__ pred_scores,
    const float4* __restrict__ priors, const int* __restrict__ gt_labels,
    const float4* __restrict__ gtb, const uint8_t* __restrict__ validb,
    const unsigned int* __restrict__ acc, float* __restrict__ out,
    int B, int P, int G, int C)
{
  int b = blockIdx.y;
  int p = blockIdx.x * 256 + threadIdx.x;
  __shared__ float4 sg[MAXG];
  __shared__ int sl[MAXG];
  __shared__ float2 sc[MAXG];
  for (int i = threadIdx.x; i < G; i += 256){
    float4 gbx = gtb[b*G + i];
    sg[i] = gbx; sl[i] = gt_labels[b*G + i];
    sc[i] = make_float2((gbx.x + gbx.z) * 0.5f, (gbx.y + gbx.w) * 0.5f);
  }
  __syncthreads();
  if (p >= P) return;
  size_t o = (size_t)b * P + p;
  unsigned int w = acc[o];
  int cnt = (int)(w >> 17);
  bool fg = cnt > 0;
  int mg = 0;
  float4 pb = pred_bboxes[o];
  if (cnt == 1){
    mg = (int)((w >> 2) & 0x7FFFu);
  } else if (cnt > 1){
    bool vld = validb[o] != 0;
    if (vld){
      float4 pr = priors[p];
      float bd = __builtin_inff(); int gd = 0;
      for (int gg = 0; gg < G; ++gg){
        float dx = pr.x - sc[gg].x, dy = pr.y - sc[gg].y;
        float d = sqrtf(dx*dx + dy*dy) / pr.z;
        if (d < bd){ bd = d; gd = gg; }
      }
      float s0 = pred_scores[o * C + sl[gd]];
      float bestc = cost_full(iou_fn(pb, sg[gd]), s0, bd);
      mg = gd;
      for (int gg = 0; gg < G; ++gg){
        float dx = pr.x - sc[gg].x, dy = pr.y - sc[gg].y;
        float d = sqrtf(dx*dx + dy*dy) / pr.z;
        float lb = exp2f((d - 3.0f) * 3.321928f) * 0.9999f - 1e-6f; // <= powf(10,d-3)
        if (lb > bestc) continue;
        float s = pred_scores[o * C + sl[gg]];
        float c = cost_full(iou_fn(pb, sg[gg]), s, d);
        if (c < bestc || (c == bestc && gg < mg)){ bestc = c; mg = gg; }
      }
    } else {
      mg = 0;  // all costs 1e8 -> argmin = 0
    }
  }
  size_t BP = (size_t)B * P;
  out[o] = fg ? (float)sl[mg] : 80.0f;            // assigned_labels
  out[BP + o] = 1.0f;                             // assigned_labels_weights
  float4 ob = fg ? sg[mg] : make_float4(0.f, 0.f, 0.f, 0.f);
  ((float4*)(out + 2*BP))[o] = ob;                // assigned_bboxes
  out[6*BP + o] = fg ? iou_fn(pb, sg[mg]) : 0.0f; // assign_metrics
  out[7*BP + o] = ((w >> 1) & 1u) ? 1.0f : 0.0f;  // fg_mask_pre_prior
}

extern "C" void kernel_launch(void* const* d_in, const int* in_sizes, int n_in,
                              void* d_out, int out_size, void* d_ws, size_t ws_size,
                              hipStream_t stream)
{
  const float4* pred_bboxes = (const float4*)d_in[0];
  const float*  pred_scores = (const float*)d_in[1];
  const float4* priors      = (const float4*)d_in[2];
  const int*    gt_labels   = (const int*)d_in[3];
  const float4* gt_bboxes   = (const float4*)d_in[4];
  const float*  pad         = (const float*)d_in[5];
  int P = in_sizes[2] / 4;                 // 8400
  int B = in_sizes[0] / (P * 4);           // 16
  int C = in_sizes[1] / (B * P);           // 80
  int G = in_sizes[4] / (B * 4);           // 100
  int BG = B * G;

  uint8_t* ws = (uint8_t*)d_ws;
  size_t fixed = (size_t)B * P * 5;        // valid (1B) + acc (4B), 672000 (8B-aligned)
  int S = 8;
  while (S > 1 && fixed + 3ull * BG * S * TK * 8 > ws_size) S >>= 1;
  int PS = (P + S - 1) / S;

  uint8_t* valid = ws;
  unsigned int* acc = (unsigned int*)(ws + (size_t)B * P);
  unsigned long long* wsM = (unsigned long long*)(ws + fixed);
  unsigned long long* wsC = wsM + (size_t)BG * S * TK;
  unsigned long long* wsI = wsC + (size_t)BG * S * TK;
  float* out = (float*)d_out;

  dim3 gridA((P + 255) / 256, B);
  k_valid<<<gridA, 256, 0, stream>>>(priors, gt_bboxes, pad, valid, acc, P, G);
  k_scan<<<dim3(BG, S), 64, 0, stream>>>(pred_bboxes, pred_scores, priors, gt_labels, gt_bboxes,
                                         pad, valid, wsM, wsC, wsI, P, G, C, S, PS);
  k_merge<<<BG, 64, 0, stream>>>(wsM, wsC, wsI, pad, acc, P, G, S);
  k_final<<<gridA, 256, 0, stream>>>(pred_bboxes, pred_scores, priors, gt_labels, gt_bboxes,
                                     valid, acc, out, B, P, G, C);
}

// Round 5
// 439.769 us; speedup vs baseline: 1.0879x; 1.0879x over previous
//
#include <hip/hip_runtime.h>
#include <cstdint>
#include <climits>
#include <cstddef>

#define TK 13
#define MAXG 128

__device__ __forceinline__ float iou_fn(const float4 pb, const float4 gb){
  float pa = (pb.z - pb.x) * (pb.w - pb.y);
  float ga = (gb.z - gb.x) * (gb.w - gb.y);
  float ltx = fmaxf(pb.x, gb.x), lty = fmaxf(pb.y, gb.y);
  float rbx = fminf(pb.z, gb.z), rby = fminf(pb.w, gb.w);
  float w = fmaxf(rbx - ltx, 0.0f), h = fmaxf(rby - lty, 0.0f);
  float inter = w * h;
  float uni = pa + ga - inter;
  return inter / fmaxf(uni, 1e-6f);
}

__device__ __forceinline__ float sigmoid_f(float x){ return 1.0f / (1.0f + expf(-x)); }

// Same expression order as R0-R4 (passed absmax 0) — do not alter.
__device__ __forceinline__ float cost_full(float iou, float s, float dist){
  float sig = sigmoid_f(s);
  float iouc = -logf(iou + 1e-7f) * 3.0f;
  float scale = iou - sig;
  float bce = fmaxf(s, 0.0f) + log1pf(expf(-fabsf(s))) - s * iou;
  float cls = bce * scale * scale;
  float soft = powf(10.0f, dist - 3.0f);
  return cls + iouc + soft;
}

// descending u64 sorted-insert, list[0] largest; sentinel 0
__device__ __forceinline__ void ins13(unsigned long long* a, unsigned long long k){
  if (k <= a[TK-1]) return;
  #pragma unroll
  for (int j = 0; j < TK; ++j){
    if (k > a[j]){ unsigned long long t = a[j]; a[j] = k; k = t; }
  }
}

__device__ __forceinline__ void bfly_max_u64(unsigned long long &v, int &l){
  #pragma unroll
  for (int off = 32; off >= 1; off >>= 1){
    unsigned long long ov = __shfl_xor(v, off);
    int ol = __shfl_xor(l, off);
    if (ov > v){ v = ov; l = ol; }
  }
}

// per-wave: 13th-largest of one key per lane (0 if fewer than 13 nonzero).
__device__ __forceinline__ unsigned long long red13(unsigned long long k, int lane){
  unsigned long long w = 0;
  for (int r = 0; r < TK; ++r){
    unsigned long long v = k; int l = lane;
    bfly_max_u64(v, l);
    w = v;
    if (lane == l) k = 0;
  }
  return w;
}

// one wave merges 128 sorted desc lists (2 per lane) in L[128*TK]; r-th winner on lane r.
__device__ __forceinline__ unsigned long long merge128(const unsigned long long* L, int lane){
  unsigned long long h0 = L[(2*lane)*TK];
  unsigned long long h1 = L[(2*lane+1)*TK];
  int p0 = 0, p1 = 0;
  unsigned long long w = 0;
  for (int r = 0; r < TK; ++r){
    unsigned long long m = h0 > h1 ? h0 : h1; int l = lane;
    bfly_max_u64(m, l);
    if (lane == r) w = m;
    if (lane == l){
      if (m == h0){ p0++; h0 = (p0 < TK) ? L[(2*lane)*TK + p0] : 0ull; }
      else        { p1++; h1 = (p1 < TK) ? L[(2*lane+1)*TK + p1] : 0ull; }
    }
  }
  return w;
}

// Kernel A: valid_mask + acc init.
__global__ __launch_bounds__(256) void k_valid(
    const float4* __restrict__ priors, const float4* __restrict__ gtb,
    const float* __restrict__ pad, uint8_t* __restrict__ valid,
    unsigned int* __restrict__ acc, int P, int G)
{
  int b = blockIdx.y;
  int p = blockIdx.x * 256 + threadIdx.x;
  __shared__ float4 sg[MAXG];
  __shared__ float sp[MAXG];
  for (int i = threadIdx.x; i < G; i += 256){ sg[i] = gtb[b*G + i]; sp[i] = pad[b*G + i]; }
  __syncthreads();
  if (p >= P) return;
  float4 pr = priors[p];
  bool v = false;
  for (int g = 0; g < G; ++g){
    float4 gb = sg[g];
    bool ig = (pr.x > gb.x) && (pr.y > gb.y) && (gb.z > pr.x) && (gb.w > pr.y);
    v = v || (ig && sp[g] > 0.5f);
  }
  size_t o = (size_t)b * P + p;
  valid[o] = v ? 1 : 0;
  acc[o] = 0u;
}

// Kernel B1: one 2-wave block per (b,g,slice). Slice = chunks c≡s (mod S) of 128
// priors. Pruned scan (block-shared thresholds, early red13 activation, prefetch);
// concurrent metric/cost merges (wave0/wave1); slice top-13s -> ws.
__global__ __launch_bounds__(128) void k_scan(
    const float4* __restrict__ pred_bboxes, const float* __restrict__ pred_scores,
    const float4* __restrict__ priors, const int* __restrict__ gt_labels,
    const float4* __restrict__ gtbb, const float* __restrict__ pad,
    const uint8_t* __restrict__ validb,
    unsigned long long* __restrict__ wsM, unsigned long long* __restrict__ wsC,
    unsigned long long* __restrict__ wsI,
    int P, int G, int C, int S)
{
  int bg = blockIdx.x;
  int s  = blockIdx.y;
  if (pad[bg] <= 0.5f) return;
  int b = bg / G;
  int tid = threadIdx.x;
  int lane = tid & 63;
  float4 gb = gtbb[bg];
  int lbl = gt_labels[bg];
  float gcx = (gb.x + gb.z) * 0.5f, gcy = (gb.y + gb.w) * 0.5f;
  size_t bP = (size_t)b * P;

  __shared__ unsigned long long slistM[128 * TK];
  __shared__ unsigned long long slistC[128 * TK];
  __shared__ unsigned int shw[2];  // [0]=cost 13th bits (min), [1]=metric 13th bits (max)
  if (tid == 0){ shw[0] = __float_as_uint(1e38f); shw[1] = 0u; }
  __syncthreads();

  unsigned long long ml[TK], cl[TK];
  float ivl[TK];
  #pragma unroll
  for (int j = 0; j < TK; ++j){ ml[j] = 0ull; cl[j] = 0ull; ivl[j] = -1.0f; }

  unsigned cmLast = 0u; float thr = 1e30f;
  int nCh = (P + 127) >> 7;
  int c = s;
  int p = c * 128 + tid;
  bool inb = p < P;
  float4 pr = make_float4(0,0,0,0), pb = pr; bool vb = false;
  if (inb){ pr = priors[p]; pb = pred_bboxes[bP + p]; vb = validb[bP + p] != 0; }
  int it = 0;
  while (c < nCh){
    // prefetch next chunk
    int cn = c + S;
    int pn = cn * 128 + tid;
    bool inbn = (cn < nCh) && (pn < P);
    float4 prn = make_float4(0,0,0,0), pbn = prn; bool vbn = false;
    if (inbn){ prn = priors[pn]; pbn = pred_bboxes[bP + pn]; vbn = validb[bP + pn] != 0; }
    // process current
    if (inb){
      float iou = iou_fn(pb, gb);
      if (iou > ivl[TK-1]){
        float v = iou;
        #pragma unroll
        for (int j = 0; j < TK; ++j){ if (v > ivl[j]){ float t = ivl[j]; ivl[j] = v; v = t; } }
      }
      bool ig = (pr.x > gb.x) && (pr.y > gb.y) && (gb.z > pr.x) && (gb.w > pr.y);
      unsigned cm = shw[0];
      if (cm != cmLast){ cmLast = cm; thr = 3.0f + log10f(__uint_as_float(cm) * 1.00002f + 1e-6f); }
      float mB = __uint_as_float(shw[1]);
      float i2 = iou * iou;
      float bnd = (i2 * i2) * i2 * 1.000002f;     // >= sigmoid*powf(iou,6)
      bool need_m = ig && !(bnd < mB);
      float dist = 0.0f; bool need_c = false;
      if (vb){
        float dx = pr.x - gcx, dy = pr.y - gcy;
        dist = sqrtf(dx*dx + dy*dy) / pr.z;
        need_c = !(dist > thr);
      }
      float sc = 0.0f;
      if (need_m || need_c) sc = pred_scores[(bP + p) * C + lbl];
      if (need_m){
        float met = sigmoid_f(sc) * powf(iou, 6.0f);
        unsigned long long k = ((unsigned long long)__float_as_uint(met) << 32)
                             | (unsigned)~(unsigned)((p << 1) | 1);
        ins13(ml, k);
        unsigned m13 = (unsigned)(ml[TK-1] >> 32);
        if (ml[TK-1] != 0ull && __uint_as_float(m13) > mB) atomicMax(&shw[1], m13);
      } else if (!ig){
        ins13(ml, (unsigned long long)(unsigned)~(unsigned)(p << 1));  // metric==0, index tie
      }
      if (!vb || need_c){
        float cst = vb ? cost_full(iou, sc, dist) : 1e8f;
        unsigned long long k = ~(((unsigned long long)__float_as_uint(cst) << 32) | (unsigned)p);
        if (k > cl[TK-1]){
          ins13(cl, k);
          if (cl[TK-1] != 0ull){
            unsigned cb = (unsigned)((~cl[TK-1]) >> 32);
            if (cb < cmLast || cmLast == 0u) atomicMin(&shw[0], cb);
          }
        }
      }
    }
    // early bound activation (per-wave 13th-of-lane-best; sound: 13 better entries exist)
    if (it == 0 || it == 1 || it == 3){
      unsigned long long wc = red13(cl[0], lane);
      if (lane == 0 && wc != 0ull) atomicMin(&shw[0], (unsigned)((~wc) >> 32));
      if (it == 0){
        unsigned long long wm = red13(ml[0], lane);
        if (lane == 0 && wm != 0ull){
          unsigned vbits = (unsigned)(wm >> 32);
          if (vbits) atomicMax(&shw[1], vbits);
        }
      }
    }
    c = cn; p = pn; inb = inbn; pr = prn; pb = pbn; vb = vbn; ++it;
  }

  size_t base = ((size_t)bg * S + s) * TK;
  #pragma unroll
  for (int j = 0; j < TK; ++j){ slistM[tid*TK + j] = ml[j]; slistC[tid*TK + j] = cl[j]; }
  __syncthreads();
  if (tid < 64){
    unsigned long long w = merge128(slistM, tid);        // metric (wave0)
    if (tid < TK) wsM[base + tid] = w;
  } else {
    unsigned long long w = merge128(slistC, tid - 64);   // cost (wave1, concurrent)
    if (tid - 64 < TK) wsC[base + (tid - 64)] = w;
  }
  __syncthreads();
  #pragma unroll
  for (int j = 0; j < TK; ++j){
    float v = ivl[j] > 0.0f ? ivl[j] : 0.0f;
    slistM[tid*TK + j] = ((unsigned long long)__float_as_uint(v) << 32) | (unsigned)(tid*TK + j + 1);
  }
  __syncthreads();
  if (tid < 64){
    unsigned long long w = merge128(slistM, tid);        // iou
    if (tid < TK) wsI[base + tid] = (w & 0xFFFFFFFF00000000ull) | (unsigned)(s*TK + tid + 1);
  }
}

// Kernel B2: one wave per (b,g). Merge S*13 slice winners per criterion (keys
// globally unique since p is partitioned across slices); scatter into acc.
__global__ __launch_bounds__(64) void k_merge(
    const unsigned long long* __restrict__ wsM, const unsigned long long* __restrict__ wsC,
    const unsigned long long* __restrict__ wsI, const float* __restrict__ pad,
    unsigned int* __restrict__ acc, int P, int G, int S)
{
  int bg = blockIdx.x;
  if (pad[bg] <= 0.5f) return;
  int b = bg / G;
  int g = bg - b * G;
  int lane = threadIdx.x;
  size_t bP = (size_t)b * P;
  int n = S * TK;
  // ---- metric -> fg marks ----
  {
    const unsigned long long* base = wsM + (size_t)bg * n;
    unsigned long long k0 = (lane < n) ? base[lane] : 0ull;
    unsigned long long k1 = (lane + 64 < n) ? base[lane + 64] : 0ull;
    for (int r = 0; r < TK; ++r){
      unsigned long long m = k0 > k1 ? k0 : k1; int l = lane;
      bfly_max_u64(m, l);
      if (m == 0ull) break;
      if (lane == 0){
        unsigned ix = ~(unsigned)(m & 0xFFFFFFFFull);
        if (ix & 1u) atomicOr(&acc[bP + (ix >> 1)], 2u);
      }
      if (lane == l){ if (k0 == m) k0 = 0ull; else k1 = 0ull; }
    }
  }
  // ---- iou -> dynamic_k (desc-order sum) ----
  int kd;
  {
    const unsigned long long* base = wsI + (size_t)bg * n;
    unsigned long long k0 = (lane < n) ? base[lane] : 0ull;
    unsigned long long k1 = (lane + 64 < n) ? base[lane + 64] : 0ull;
    float ksum = 0.0f;
    for (int r = 0; r < TK; ++r){
      unsigned long long m = k0 > k1 ? k0 : k1; int l = lane;
      bfly_max_u64(m, l);
      ksum += __uint_as_float((unsigned)(m >> 32));
      if (lane == l){ if (k0 == m) k0 = 0ull; else k1 = 0ull; }
    }
    kd = (int)ksum; if (kd < 1) kd = 1;
  }
  // ---- cost -> emit first kd selections ----
  {
    const unsigned long long* base = wsC + (size_t)bg * n;
    unsigned long long k0 = (lane < n) ? base[lane] : 0ull;
    unsigned long long k1 = (lane + 64 < n) ? base[lane + 64] : 0ull;
    for (int r = 0; r < kd; ++r){
      unsigned long long m = k0 > k1 ? k0 : k1; int l = lane;
      bfly_max_u64(m, l);
      if (m == 0ull) break;
      if (lane == 0){
        unsigned long long key = ~m;
        unsigned p = (unsigned)(key & 0xFFFFFFFFull);
        atomicAdd(&acc[bP + p], (1u << 17) | ((unsigned)g << 2));
      }
      if (lane == l){ if (k0 == m) k0 = 0ull; else k1 = 0ull; }
    }
  }
}

// Kernel C: per (b,p) decode acc; multi-match -> dist-pruned argmin-cost; write outputs.
__global__ __launch_bounds__(256) void k_final(
    const float4* __restrict__ pred_bboxes, const float* __restrict__ pred_scores,
    const float4* __restrict__ priors, const int* __restrict__ gt_labels,
    const float4* __restrict__ gtb, const uint8_t* __restrict__ validb,
    const unsigned int* __restrict__ acc, float* __restrict__ out,
    int B, int P, int G, int C)
{
  int b = blockIdx.y;
  int p = blockIdx.x * 256 + threadIdx.x;
  __shared__ float4 sg[MAXG];
  __shared__ int sl[MAXG];
  __shared__ float2 sc[MAXG];
  for (int i = threadIdx.x; i < G; i += 256){
    float4 gbx = gtb[b*G + i];
    sg[i] = gbx; sl[i] = gt_labels[b*G + i];
    sc[i] = make_float2((gbx.x + gbx.z) * 0.5f, (gbx.y + gbx.w) * 0.5f);
  }
  __syncthreads();
  if (p >= P) return;
  size_t o = (size_t)b * P + p;
  unsigned int w = acc[o];
  int cnt = (int)(w >> 17);
  bool fg = cnt > 0;
  int mg = 0;
  float4 pb = pred_bboxes[o];
  if (cnt == 1){
    mg = (int)((w >> 2) & 0x7FFFu);
  } else if (cnt > 1){
    bool vld = validb[o] != 0;
    if (vld){
      float4 pr = priors[p];
      const float* srow = pred_scores + o * C;
      // pass 1: d^2-based closest gt as seed (seed choice doesn't affect exactness)
      float bd2 = __builtin_inff(); int gd = 0;
      for (int gg = 0; gg < G; ++gg){
        float dx = pr.x - sc[gg].x, dy = pr.y - sc[gg].y;
        float d2 = dx*dx + dy*dy;
        if (d2 < bd2){ bd2 = d2; gd = gg; }
      }
      {
        float dx = pr.x - sc[gd].x, dy = pr.y - sc[gd].y;
        float d = sqrtf(dx*dx + dy*dy) / pr.z;
        float bestc = cost_full(iou_fn(pb, sg[gd]), srow[sl[gd]], d);
        mg = gd;
        // pass 2: exact argmin with safe soft-center lower-bound pruning
        for (int gg = 0; gg < G; ++gg){
          float dxx = pr.x - sc[gg].x, dyy = pr.y - sc[gg].y;
          float dd = sqrtf(dxx*dxx + dyy*dyy) / pr.z;
          float lb = exp2f((dd - 3.0f) * 3.321928f) * 0.9999f - 1e-6f; // <= powf(10,dd-3)
          if (lb > bestc) continue;
          float cc = cost_full(iou_fn(pb, sg[gg]), srow[sl[gg]], dd);
          if (cc < bestc || (cc == bestc && gg < mg)){ bestc = cc; mg = gg; }
        }
      }
    } else {
      mg = 0;  // all costs 1e8 -> argmin = 0
    }
  }
  size_t BP = (size_t)B * P;
  out[o] = fg ? (float)sl[mg] : 80.0f;            // assigned_labels
  out[BP + o] = 1.0f;                             // assigned_labels_weights
  float4 ob = fg ? sg[mg] : make_float4(0.f, 0.f, 0.f, 0.f);
  ((float4*)(out + 2*BP))[o] = ob;                // assigned_bboxes
  out[6*BP + o] = fg ? iou_fn(pb, sg[mg]) : 0.0f; // assign_metrics
  out[7*BP + o] = ((w >> 1) & 1u) ? 1.0f : 0.0f;  // fg_mask_pre_prior
}

extern "C" void kernel_launch(void* const* d_in, const int* in_sizes, int n_in,
                              void* d_out, int out_size, void* d_ws, size_t ws_size,
                              hipStream_t stream)
{
  const float4* pred_bboxes = (const float4*)d_in[0];
  const float*  pred_scores = (const float*)d_in[1];
  const float4* priors      = (const float4*)d_in[2];
  const int*    gt_labels   = (const int*)d_in[3];
  const float4* gt_bboxes   = (const float4*)d_in[4];
  const float*  pad         = (const float*)d_in[5];
  int P = in_sizes[2] / 4;                 // 8400
  int B = in_sizes[0] / (P * 4);           // 16
  int C = in_sizes[1] / (B * P);           // 80
  int G = in_sizes[4] / (B * 4);           // 100
  int BG = B * G;

  uint8_t* ws = (uint8_t*)d_ws;
  size_t fixed = (size_t)B * P * 5;        // valid (1B) + acc (4B)
  int S = 2;
  while (S > 1 && fixed + 3ull * BG * S * TK * 8 > ws_size) S >>= 1;

  uint8_t* valid = ws;
  unsigned int* acc = (unsigned int*)(ws + (size_t)B * P);
  unsigned long long* wsM = (unsigned long long*)(ws + fixed);
  unsigned long long* wsC = wsM + (size_t)BG * S * TK;
  unsigned long long* wsI = wsC + (size_t)BG * S * TK;
  float* out = (float*)d_out;

  dim3 gridA((P + 255) / 256, B);
  k_valid<<<gridA, 256, 0, stream>>>(priors, gt_bboxes, pad, valid, acc, P, G);
  k_scan<<<dim3(BG, S), 128, 0, stream>>>(pred_bboxes, pred_scores, priors, gt_labels, gt_bboxes,
                                          pad, valid, wsM, wsC, wsI, P, G, C, S);
  k_merge<<<BG, 64, 0, stream>>>(wsM, wsC, wsI, pad, acc, P, G, S);
  k_final<<<gridA, 256, 0, stream>>>(pred_bboxes, pred_scores, priors, gt_labels, gt_bboxes,
                                     valid, acc, out, B, P, G, C);
}

// Round 6
// 433.198 us; speedup vs baseline: 1.1044x; 1.0152x over previous
//
#include <hip/hip_runtime.h>
#include <cstdint>
#include <climits>
#include <cstddef>

#define TK 13
#define MAXG 128

__device__ __forceinline__ float iou_fn(const float4 pb, const float4 gb){
  float pa = (pb.z - pb.x) * (pb.w - pb.y);
  float ga = (gb.z - gb.x) * (gb.w - gb.y);
  float ltx = fmaxf(pb.x, gb.x), lty = fmaxf(pb.y, gb.y);
  float rbx = fminf(pb.z, gb.z), rby = fminf(pb.w, gb.w);
  float w = fmaxf(rbx - ltx, 0.0f), h = fmaxf(rby - lty, 0.0f);
  float inter = w * h;
  float uni = pa + ga - inter;
  return inter / fmaxf(uni, 1e-6f);
}

__device__ __forceinline__ float sigmoid_f(float x){ return 1.0f / (1.0f + expf(-x)); }

// Same expression order as R0-R5 (passed absmax 0) — do not alter.
__device__ __forceinline__ float cost_full(float iou, float s, float dist){
  float sig = sigmoid_f(s);
  float iouc = -logf(iou + 1e-7f) * 3.0f;
  float scale = iou - sig;
  float bce = fmaxf(s, 0.0f) + log1pf(expf(-fabsf(s))) - s * iou;
  float cls = bce * scale * scale;
  float soft = powf(10.0f, dist - 3.0f);
  return cls + iouc + soft;
}

// descending u64 sorted-insert, list[0] largest; sentinel 0
__device__ __forceinline__ void ins13(unsigned long long* a, unsigned long long k){
  if (k <= a[TK-1]) return;
  #pragma unroll
  for (int j = 0; j < TK; ++j){
    if (k > a[j]){ unsigned long long t = a[j]; a[j] = k; k = t; }
  }
}

__device__ __forceinline__ void bfly_max_u64(unsigned long long &v, int &l){
  #pragma unroll
  for (int off = 32; off >= 1; off >>= 1){
    unsigned long long ov = __shfl_xor(v, off);
    int ol = __shfl_xor(l, off);
    if (ov > v){ v = ov; l = ol; }
  }
}

__device__ __forceinline__ unsigned long long wave_max_u64(unsigned long long v){
  #pragma unroll
  for (int off = 32; off >= 1; off >>= 1){
    unsigned long long ov = __shfl_xor(v, off);
    if (ov > v) v = ov;
  }
  return v;
}

// 13th-largest of one key per lane (0 if fewer than 13 nonzero). All lanes get it.
__device__ __forceinline__ unsigned long long red13(unsigned long long k, int lane){
  unsigned long long w = 0;
  for (int r = 0; r < TK; ++r){
    unsigned long long v = k; int l = lane;
    bfly_max_u64(v, l);
    w = v;
    if (lane == l) k = 0;
  }
  return w;
}

// one wave merges 64 sorted desc lists (1/lane) in L[64*TK]; r-th winner on lane r.
__device__ __forceinline__ unsigned long long merge64(const unsigned long long* L, int lane){
  int ptr = 0;
  unsigned long long h = L[lane*TK];
  unsigned long long w = 0;
  for (int r = 0; r < TK; ++r){
    unsigned long long v = h; int l = lane;
    bfly_max_u64(v, l);
    if (lane == r) w = v;
    if (lane == l){ ptr++; h = (ptr < TK) ? L[lane*TK + ptr] : 0ull; }
  }
  return w;
}

// Kernel A: valid bitmask (ballot per wave) + acc init.
__global__ __launch_bounds__(256) void k_valid(
    const float4* __restrict__ priors, const float4* __restrict__ gtb,
    const float* __restrict__ pad, unsigned long long* __restrict__ vmask,
    unsigned int* __restrict__ acc, int P, int G, int nCh)
{
  int b = blockIdx.y;
  int p = blockIdx.x * 256 + threadIdx.x;
  __shared__ float4 sg[MAXG];
  __shared__ float sp[MAXG];
  for (int i = threadIdx.x; i < G; i += 256){ sg[i] = gtb[b*G + i]; sp[i] = pad[b*G + i]; }
  __syncthreads();
  if (p >= P) return;
  float4 pr = priors[p];
  bool v = false;
  #pragma unroll 4
  for (int g = 0; g < G; ++g){
    float4 gb = sg[g];
    bool ig = (pr.x > gb.x) && (pr.y > gb.y) && (gb.z > pr.x) && (gb.w > pr.y);
    v = v || (ig && sp[g] > 0.5f);
  }
  size_t o = (size_t)b * P + p;
  acc[o] = 0u;
  unsigned long long m = __ballot(v);
  if ((threadIdx.x & 63) == 0) vmask[(size_t)b * nCh + (p >> 6)] = m;
}

// Kernel B1: one single-wave block per (b,g,slice). Slice = chunks c≡s (mod S)
// of 64 priors. Register-only wave-uniform prune bounds (no LDS atomics);
// per-lane top-13 u64 lists; slice top-13s -> ws.
__global__ __launch_bounds__(64) void k_scan(
    const float4* __restrict__ pred_bboxes, const float* __restrict__ pred_scores,
    const float4* __restrict__ priors, const int* __restrict__ gt_labels,
    const float4* __restrict__ gtbb, const float* __restrict__ pad,
    const unsigned long long* __restrict__ vmask,
    unsigned long long* __restrict__ wsM, unsigned long long* __restrict__ wsC,
    unsigned long long* __restrict__ wsI,
    int P, int G, int C, int S, int nCh)
{
  int bg = blockIdx.x;
  int s  = blockIdx.y;
  if (pad[bg] <= 0.5f) return;
  int b = bg / G;
  int lane = threadIdx.x;
  float4 gb = gtbb[bg];
  int lbl = gt_labels[bg];
  float gcx = (gb.x + gb.z) * 0.5f, gcy = (gb.y + gb.w) * 0.5f;
  size_t bP = (size_t)b * P;
  const unsigned long long* vmb = vmask + (size_t)b * nCh;

  __shared__ unsigned long long slist[64 * TK];

  unsigned long long ml[TK], cl[TK];
  float ivl[TK];
  #pragma unroll
  for (int j = 0; j < TK; ++j){ ml[j] = 0ull; cl[j] = 0ull; ivl[j] = -1.0f; }

  float thr = 1e30f;   // dist prune threshold (wave-uniform)
  float mB  = 0.0f;    // metric prune bound (wave-uniform)

  int c = s;
  int p = c * 64 + lane;
  bool inb = p < P;
  float4 pr = make_float4(0,0,0,0), pb = pr; bool vb = false;
  if (inb){ pr = priors[p]; pb = pred_bboxes[bP + p]; vb = (vmb[c] >> lane) & 1ull; }
  int it = 0;
  while (c < nCh){
    int cn = c + S;
    int pn = cn * 64 + lane;
    bool inbn = (cn < nCh) && (pn < P);
    float4 prn = make_float4(0,0,0,0), pbn = prn; bool vbn = false;
    if (inbn){ prn = priors[pn]; pbn = pred_bboxes[bP + pn]; vbn = (vmb[cn] >> lane) & 1ull; }
    if (inb){
      float iou = iou_fn(pb, gb);
      if (iou > ivl[TK-1]){
        float v = iou;
        #pragma unroll
        for (int j = 0; j < TK; ++j){ if (v > ivl[j]){ float t = ivl[j]; ivl[j] = v; v = t; } }
      }
      bool ig = (pr.x > gb.x) && (pr.y > gb.y) && (gb.z > pr.x) && (gb.w > pr.y);
      float i2 = iou * iou;
      float bnd = (i2 * i2) * i2 * 1.000002f;     // >= sigmoid*powf(iou,6)
      bool need_m = ig && !(bnd < mB);
      float dist = 0.0f; bool need_c = false;
      if (vb){
        float dx = pr.x - gcx, dy = pr.y - gcy;
        dist = sqrtf(dx*dx + dy*dy) / pr.z;
        need_c = !(dist > thr);
      }
      float sc = 0.0f;
      if (need_m || need_c) sc = pred_scores[(bP + p) * C + lbl];
      if (need_m){
        float met = sigmoid_f(sc) * powf(iou, 6.0f);
        ins13(ml, ((unsigned long long)__float_as_uint(met) << 32)
                  | (unsigned)~(unsigned)((p << 1) | 1));
      } else if (!ig){
        ins13(ml, (unsigned long long)(unsigned)~(unsigned)(p << 1));  // metric==0, index tie
      }
      if (!vb || need_c){
        float cst = vb ? cost_full(iou, sc, dist) : 1e8f;
        ins13(cl, ~(((unsigned long long)__float_as_uint(cst) << 32) | (unsigned)p));
      }
    }
    // wave-uniform bound refresh (register-only; sound upper bounds on block 13th-best)
    if (it == 0 || it == 1 || it == 3 || it == 7){
      unsigned long long kb = wave_max_u64(cl[TK-1]);
      if (it == 0){
        unsigned long long k2 = red13(cl[0], lane);
        if (k2 > kb) kb = k2;
      }
      if (kb != 0ull){
        float cb = __uint_as_float((unsigned)((~kb) >> 32));
        float nthr = 3.0f + log10f(cb * 1.00002f + 1e-6f);
        thr = fminf(thr, nthr);
      }
      if (it == 0 || it == 3){
        unsigned long long km = wave_max_u64(ml[TK-1]);
        if (it == 0){
          unsigned long long k2 = red13(ml[0], lane);
          if (k2 > km) km = k2;
        }
        float mb2 = __uint_as_float((unsigned)(km >> 32));
        if (mb2 > mB) mB = mb2;
      }
    }
    c = cn; p = pn; inb = inbn; pr = prn; pb = pbn; vb = vbn; ++it;
  }

  size_t base = ((size_t)bg * S + s) * TK;
  // metric
  #pragma unroll
  for (int j = 0; j < TK; ++j) slist[lane*TK + j] = ml[j];
  __syncthreads();
  { unsigned long long w = merge64(slist, lane); if (lane < TK) wsM[base + lane] = w; }
  __syncthreads();
  // cost
  #pragma unroll
  for (int j = 0; j < TK; ++j) slist[lane*TK + j] = cl[j];
  __syncthreads();
  { unsigned long long w = merge64(slist, lane); if (lane < TK) wsC[base + lane] = w; }
  __syncthreads();
  // iou (block-unique low bits; rewritten globally unique on write)
  #pragma unroll
  for (int j = 0; j < TK; ++j){
    float v = ivl[j] > 0.0f ? ivl[j] : 0.0f;
    slist[lane*TK + j] = ((unsigned long long)__float_as_uint(v) << 32) | (unsigned)(lane*TK + j + 1);
  }
  __syncthreads();
  { unsigned long long w = merge64(slist, lane);
    if (lane < TK) wsI[base + lane] = (w & 0xFFFFFFFF00000000ull) | (unsigned)(s*TK + lane + 1); }
}

// Kernel B2: one wave per (b,g). Merge S*13 slice winners per criterion (keys
// globally unique, p partitioned across slices); scatter into acc.
__global__ __launch_bounds__(64) void k_merge(
    const unsigned long long* __restrict__ wsM, const unsigned long long* __restrict__ wsC,
    const unsigned long long* __restrict__ wsI, const float* __restrict__ pad,
    unsigned int* __restrict__ acc, int P, int G, int S)
{
  int bg = blockIdx.x;
  if (pad[bg] <= 0.5f) return;
  int b = bg / G;
  int g = bg - b * G;
  int lane = threadIdx.x;
  size_t bP = (size_t)b * P;
  int n = S * TK;
  // metric -> fg marks
  {
    const unsigned long long* base = wsM + (size_t)bg * n;
    unsigned long long k0 = (lane < n) ? base[lane] : 0ull;
    unsigned long long k1 = (lane + 64 < n) ? base[lane + 64] : 0ull;
    for (int r = 0; r < TK; ++r){
      unsigned long long m = k0 > k1 ? k0 : k1; int l = lane;
      bfly_max_u64(m, l);
      if (m == 0ull) break;
      if (lane == 0){
        unsigned ix = ~(unsigned)(m & 0xFFFFFFFFull);
        if (ix & 1u) atomicOr(&acc[bP + (ix >> 1)], 2u);
      }
      if (lane == l){ if (k0 == m) k0 = 0ull; else k1 = 0ull; }
    }
  }
  // iou -> dynamic_k (desc-order sum)
  int kd;
  {
    const unsigned long long* base = wsI + (size_t)bg * n;
    unsigned long long k0 = (lane < n) ? base[lane] : 0ull;
    unsigned long long k1 = (lane + 64 < n) ? base[lane + 64] : 0ull;
    float ksum = 0.0f;
    for (int r = 0; r < TK; ++r){
      unsigned long long m = k0 > k1 ? k0 : k1; int l = lane;
      bfly_max_u64(m, l);
      ksum += __uint_as_float((unsigned)(m >> 32));
      if (lane == l){ if (k0 == m) k0 = 0ull; else k1 = 0ull; }
    }
    kd = (int)ksum; if (kd < 1) kd = 1;
  }
  // cost -> emit first kd selections
  {
    const unsigned long long* base = wsC + (size_t)bg * n;
    unsigned long long k0 = (lane < n) ? base[lane] : 0ull;
    unsigned long long k1 = (lane + 64 < n) ? base[lane + 64] : 0ull;
    for (int r = 0; r < kd; ++r){
      unsigned long long m = k0 > k1 ? k0 : k1; int l = lane;
      bfly_max_u64(m, l);
      if (m == 0ull) break;
      if (lane == 0){
        unsigned p = (unsigned)((~m) & 0xFFFFFFFFull);
        atomicAdd(&acc[bP + p], (1u << 17) | ((unsigned)g << 2));
      }
      if (lane == l){ if (k0 == m) k0 = 0ull; else k1 = 0ull; }
    }
  }
}

// Kernel C: per (b,p) decode acc; multi-match -> dist-pruned argmin-cost; write outputs.
__global__ __launch_bounds__(256) void k_final(
    const float4* __restrict__ pred_bboxes, const float* __restrict__ pred_scores,
    const float4* __restrict__ priors, const int* __restrict__ gt_labels,
    const float4* __restrict__ gtb, const unsigned long long* __restrict__ vmask,
    const unsigned int* __restrict__ acc, float* __restrict__ out,
    int B, int P, int G, int C, int nCh)
{
  int b = blockIdx.y;
  int p = blockIdx.x * 256 + threadIdx.x;
  __shared__ float4 sg[MAXG];
  __shared__ int sl[MAXG];
  __shared__ float2 sc[MAXG];
  for (int i = threadIdx.x; i < G; i += 256){
    float4 gbx = gtb[b*G + i];
    sg[i] = gbx; sl[i] = gt_labels[b*G + i];
    sc[i] = make_float2((gbx.x + gbx.z) * 0.5f, (gbx.y + gbx.w) * 0.5f);
  }
  __syncthreads();
  if (p >= P) return;
  size_t o = (size_t)b * P + p;
  unsigned int w = acc[o];
  int cnt = (int)(w >> 17);
  bool fg = cnt > 0;
  int mg = 0;
  float4 pb = pred_bboxes[o];
  if (cnt == 1){
    mg = (int)((w >> 2) & 0x7FFFu);
  } else if (cnt > 1){
    bool vld = (vmask[(size_t)b * nCh + (p >> 6)] >> (p & 63)) & 1ull;
    if (vld){
      float4 pr = priors[p];
      const float* srow = pred_scores + o * C;
      float bd2 = __builtin_inff(); int gd = 0;
      for (int gg = 0; gg < G; ++gg){
        float dx = pr.x - sc[gg].x, dy = pr.y - sc[gg].y;
        float d2 = dx*dx + dy*dy;
        if (d2 < bd2){ bd2 = d2; gd = gg; }
      }
      float dxs = pr.x - sc[gd].x, dys = pr.y - sc[gd].y;
      float ds0 = sqrtf(dxs*dxs + dys*dys) / pr.z;
      float bestc = cost_full(iou_fn(pb, sg[gd]), srow[sl[gd]], ds0);
      mg = gd;
      for (int gg = 0; gg < G; ++gg){
        float dxx = pr.x - sc[gg].x, dyy = pr.y - sc[gg].y;
        float dd = sqrtf(dxx*dxx + dyy*dyy) / pr.z;
        float lb = exp2f((dd - 3.0f) * 3.321928f) * 0.9999f - 1e-6f; // <= powf(10,dd-3)
        if (lb > bestc) continue;
        float cc = cost_full(iou_fn(pb, sg[gg]), srow[sl[gg]], dd);
        if (cc < bestc || (cc == bestc && gg < mg)){ bestc = cc; mg = gg; }
      }
    } else {
      mg = 0;  // all costs 1e8 -> argmin = 0
    }
  }
  size_t BP = (size_t)B * P;
  out[o] = fg ? (float)sl[mg] : 80.0f;            // assigned_labels
  out[BP + o] = 1.0f;                             // assigned_labels_weights
  float4 ob = fg ? sg[mg] : make_float4(0.f, 0.f, 0.f, 0.f);
  ((float4*)(out + 2*BP))[o] = ob;                // assigned_bboxes
  out[6*BP + o] = fg ? iou_fn(pb, sg[mg]) : 0.0f; // assign_metrics
  out[7*BP + o] = ((w >> 1) & 1u) ? 1.0f : 0.0f;  // fg_mask_pre_prior
}

extern "C" void kernel_launch(void* const* d_in, const int* in_sizes, int n_in,
                              void* d_out, int out_size, void* d_ws, size_t ws_size,
                              hipStream_t stream)
{
  const float4* pred_bboxes = (const float4*)d_in[0];
  const float*  pred_scores = (const float*)d_in[1];
  const float4* priors      = (const float4*)d_in[2];
  const int*    gt_labels   = (const int*)d_in[3];
  const float4* gt_bboxes   = (const float4*)d_in[4];
  const float*  pad         = (const float*)d_in[5];
  int P = in_sizes[2] / 4;                 // 8400
  int B = in_sizes[0] / (P * 4);           // 16
  int C = in_sizes[1] / (B * P);           // 80
  int G = in_sizes[4] / (B * 4);           // 100
  int BG = B * G;
  int nCh = (P + 63) >> 6;                 // 132

  uint8_t* ws = (uint8_t*)d_ws;
  size_t accOff = (size_t)B * nCh * 8;                    // vmask
  size_t fixed  = accOff + (size_t)B * P * 4;             // + acc
  fixed = (fixed + 7) & ~(size_t)7;
  int S = 4;
  while (S > 1 && fixed + 3ull * BG * S * TK * 8 > ws_size) S >>= 1;

  unsigned long long* vmask = (unsigned long long*)ws;
  unsigned int* acc = (unsigned int*)(ws + accOff);
  unsigned long long* wsM = (unsigned long long*)(ws + fixed);
  unsigned long long* wsC = wsM + (size_t)BG * S * TK;
  unsigned long long* wsI = wsC + (size_t)BG * S * TK;
  float* out = (float*)d_out;

  dim3 gridA((P + 255) / 256, B);
  k_valid<<<gridA, 256, 0, stream>>>(priors, gt_bboxes, pad, vmask, acc, P, G, nCh);
  k_scan<<<dim3(BG, S), 64, 0, stream>>>(pred_bboxes, pred_scores, priors, gt_labels, gt_bboxes,
                                         pad, vmask, wsM, wsC, wsI, P, G, C, S, nCh);
  k_merge<<<BG, 64, 0, stream>>>(wsM, wsC, wsI, pad, acc, P, G, S);
  k_final<<<gridA, 256, 0, stream>>>(pred_bboxes, pred_scores, priors, gt_labels, gt_bboxes,
                                     vmask, acc, out, B, P, G, C, nCh);
}